// Round 7
// baseline (389.330 us; speedup 1.0000x reference)
//
#include <hip/hip_runtime.h>

#define F_IN 128
#define HID  64
#define NCLS 16

#define BSHIFT 8            // 256 nodes per bucket
#define BNODES 256
#define NB_MAX 512          // max buckets (N<=128k)
#define CHUNK  8192         // edges per scatter block
#define CAP    8192         // max edges per bucket in LDS (mean 4352, 50+ sigma margin)

// round-to-nearest-even fp32 -> bf16
__device__ __forceinline__ unsigned short f2bf(float f) {
    unsigned int u = __float_as_uint(f);
    u += 0x7FFFu + ((u >> 16) & 1u);
    return (unsigned short)(u >> 16);
}
__device__ __forceinline__ float bf2f(unsigned short h) {
    return __uint_as_float((unsigned int)h << 16);
}

// ---------- pass 1: global bucket histogram ----------
__global__ __launch_bounds__(256) void hist_kernel(const int* __restrict__ dst,
                                                   int* __restrict__ bucket_count,
                                                   int E, int NB) {
    __shared__ int hist[NB_MAX];
    int tid = threadIdx.x;
    for (int i = tid; i < NB; i += 256) hist[i] = 0;
    __syncthreads();
    int cb = blockIdx.x * CHUNK;
    for (int k = 0; k < CHUNK / 256; k++) {
        int e = cb + k * 256 + tid;
        if (e < E) atomicAdd(&hist[dst[e] >> BSHIFT], 1);
    }
    __syncthreads();
    for (int i = tid; i < NB; i += 256)
        if (hist[i]) atomicAdd(&bucket_count[i], hist[i]);
}

// ---------- pass 2: single-block scan of bucket counts ----------
__global__ __launch_bounds__(512) void scan_buckets(const int* __restrict__ bucket_count,
                                                    int* __restrict__ bucket_base,
                                                    int* __restrict__ bucket_cursor,
                                                    int* __restrict__ row_ptr,
                                                    int NB, int N, int E) {
    __shared__ int s[512];
    int tid = threadIdx.x;
    int v = (tid < NB) ? bucket_count[tid] : 0;
    s[tid] = v;
    __syncthreads();
    for (int off = 1; off < 512; off <<= 1) {
        int t = (tid >= off) ? s[tid - off] : 0;
        __syncthreads();
        s[tid] += t;
        __syncthreads();
    }
    if (tid < NB) {
        int excl = s[tid] - v;
        bucket_base[tid]   = excl;
        bucket_cursor[tid] = excl;
    }
    if (tid == 0) { bucket_base[NB] = E; row_ptr[N] = E; }
}

// ---------- pass 3: partition edges into bucket regions ----------
__global__ __launch_bounds__(256) void scatter_kernel(const int* __restrict__ src,
                                                      const int* __restrict__ dst,
                                                      int* __restrict__ bucket_cursor,
                                                      unsigned int* __restrict__ part,
                                                      int E, int NB) {
    __shared__ int hist[NB_MAX];
    __shared__ int base_s[NB_MAX];
    int tid = threadIdx.x;
    for (int i = tid; i < NB; i += 256) hist[i] = 0;
    __syncthreads();
    int cb = blockIdx.x * CHUNK;
    for (int k = 0; k < CHUNK / 256; k++) {
        int e = cb + k * 256 + tid;
        if (e < E) atomicAdd(&hist[dst[e] >> BSHIFT], 1);
    }
    __syncthreads();
    for (int i = tid; i < NB; i += 256) {
        int c = hist[i];
        base_s[i] = c ? atomicAdd(&bucket_cursor[i], c) : 0;
        hist[i] = 0;
    }
    __syncthreads();
    for (int k = 0; k < CHUNK / 256; k++) {
        int e = cb + k * 256 + tid;
        if (e < E) {
            int d = dst[e];
            int b = d >> BSHIFT;
            int pos = base_s[b] + atomicAdd(&hist[b], 1);
            part[pos] = ((unsigned int)(d & (BNODES - 1)) << 24) | (unsigned int)src[e];
        }
    }
}

// ---------- pass 4: per-bucket counting sort -> csr_src, row_ptr, dis ----------
__global__ __launch_bounds__(256) void csr_build(const unsigned int* __restrict__ part,
                                                 const int* __restrict__ bucket_base,
                                                 int* __restrict__ csr_src,
                                                 int* __restrict__ row_ptr,
                                                 float* __restrict__ dis,
                                                 int N) {
    __shared__ unsigned int eL[CAP];
    __shared__ unsigned int outL[CAP];
    __shared__ int cnt[BNODES];
    __shared__ int sc[BNODES];
    __shared__ int cur[BNODES];
    int tid = threadIdx.x;
    int b = blockIdx.x;
    int eB = bucket_base[b];
    int eN = bucket_base[b + 1] - eB;
    if (eN > CAP) eN = CAP;

    cnt[tid] = 0;
    __syncthreads();
    for (int i = tid; i < eN; i += 256) {
        unsigned int v = part[eB + i];
        eL[i] = v;
        atomicAdd(&cnt[v >> 24], 1);
    }
    __syncthreads();
    int myc = cnt[tid];
    sc[tid] = myc;
    __syncthreads();
    for (int off = 1; off < 256; off <<= 1) {
        int t = (tid >= off) ? sc[tid - off] : 0;
        __syncthreads();
        sc[tid] += t;
        __syncthreads();
    }
    int excl = sc[tid] - myc;
    cur[tid] = excl;
    int gnode = b * BNODES + tid;
    if (gnode < N) {
        row_ptr[gnode] = eB + excl;
        float d = (float)myc;
        dis[gnode] = d > 0.0f ? rsqrtf(fmaxf(d, 1.0f)) : 0.0f;
    }
    __syncthreads();
    for (int i = tid; i < eN; i += 256) {
        unsigned int v = eL[i];
        int pos = atomicAdd(&cur[v >> 24], 1);
        outL[pos] = v & 0xFFFFFFu;
    }
    __syncthreads();
    for (int i = tid; i < eN; i += 256)
        csr_src[eB + i] = (int)outL[i];
}

// ---------- gemm1: 256 threads = 4 waves; 64 rows/block; wave w computes ----------
// ---------- cols [w*16, w*16+16) over full K=128. W1 slice scalarized.    ----------
__global__ __launch_bounds__(256) void gemm1_kernel(
        const float* __restrict__ x, const float* __restrict__ W1,
        const float* __restrict__ dis, unsigned short* __restrict__ h1b, int N) {
    __shared__ float xs[64 * 132];   // 64 rows x 128 k, row stride 132 floats (33.8 KB)
    int tid = threadIdx.x;
    int w = tid >> 6;       // wave id = column group
    int lane = tid & 63;    // row within block
    int row0 = blockIdx.x * 64;
    int row = row0 + lane;

    // stage 64 rows x 32 float4, fully coalesced (8 f4 per thread)
    #pragma unroll
    for (int it = 0; it < 8; it++) {
        int f = it * 256 + tid;      // 0..2047
        int r = f >> 5;              // 32 float4 per row
        int c = f & 31;
        float4 v = make_float4(0.f, 0.f, 0.f, 0.f);
        if (row0 + r < N) v = ((const float4*)x)[(size_t)(row0 + r) * 32 + c];
        ((float4*)&xs[r * 132])[c] = v;
    }
    __syncthreads();

    float acc[16];
    #pragma unroll
    for (int j = 0; j < 16; j++) acc[j] = 0.f;

    const float* Wc = W1 + w * 16;   // this wave's 16-col slice (wave-uniform)
    #pragma unroll 1
    for (int k4 = 0; k4 < 32; k4++) {
        float4 xv = ((const float4*)&xs[lane * 132])[k4];
        const float* wr = Wc + (k4 * 4) * HID;
        #pragma unroll
        for (int kk = 0; kk < 4; kk++) {
            float xk = (&xv.x)[kk];
            #pragma unroll
            for (int j = 0; j < 16; j++)
                acc[j] = fmaf(xk, wr[kk * HID + j], acc[j]);
        }
    }

    if (row < N) {
        float dn = dis[row];
        unsigned int packed[8];
        #pragma unroll
        for (int j2 = 0; j2 < 8; j2++) {
            unsigned int lo = f2bf(acc[j2 * 2] * dn);
            unsigned int hi = f2bf(acc[j2 * 2 + 1] * dn);
            packed[j2] = lo | (hi << 16);
        }
        uint4* d4 = (uint4*)&h1b[(size_t)row * HID + w * 16];
        d4[0] = make_uint4(packed[0], packed[1], packed[2], packed[3]);
        d4[1] = make_uint4(packed[4], packed[5], packed[6], packed[7]);
    }
}

// ---------- fused layer-1 agg (bf16 gather) + ReLU + W2 GEMM ----------
__global__ __launch_bounds__(256) void agg1_fused(
        const int* __restrict__ row_ptr, const int* __restrict__ csr_src,
        const unsigned short* __restrict__ h1b, const float* __restrict__ dis,
        const float* __restrict__ b1, const float* __restrict__ W2,
        unsigned short* __restrict__ h2b, int N) {
    __shared__ float W2s[HID * NCLS];
    __shared__ float ts[4][HID];
    int tid = threadIdx.x;
    for (int i = tid; i < HID * NCLS; i += 256) W2s[i] = W2[i];
    __syncthreads();

    int w = tid >> 6;
    int lane = tid & 63;
    int n = blockIdx.x * 4 + w;

    float acc = 0.f;
    float dn = 0.f;
    if (n < N) {
        dn = dis[n];
        int beg = row_ptr[n];
        int end = row_ptr[n + 1];
        int i = beg;
        for (; i + 4 <= end; i += 4) {
            int s0 = csr_src[i];
            int s1 = csr_src[i + 1];
            int s2 = csr_src[i + 2];
            int s3 = csr_src[i + 3];
            float v0 = bf2f(h1b[(size_t)s0 * HID + lane]);
            float v1 = bf2f(h1b[(size_t)s1 * HID + lane]);
            float v2 = bf2f(h1b[(size_t)s2 * HID + lane]);
            float v3 = bf2f(h1b[(size_t)s3 * HID + lane]);
            acc += v0 + v1 + v2 + v3;
        }
        for (; i < end; i++)
            acc += bf2f(h1b[(size_t)csr_src[i] * HID + lane]);
    }

    float t = fmaxf(dn * acc + b1[lane], 0.f);
    ts[w][lane] = t;

    int q = lane >> 4;
    int c = lane & 15;
    float p = 0.f;
    #pragma unroll
    for (int jj = 0; jj < 16; jj++) {
        int j = q * 16 + jj;
        p += ts[w][j] * W2s[j * NCLS + c];
    }
    p += __shfl_xor(p, 16, 64);
    p += __shfl_xor(p, 32, 64);
    if (n < N && q == 0) h2b[(size_t)n * NCLS + c] = f2bf(p * dn);
}

// ---------- fused layer-2 agg (bf16 gather) + epilogue ----------
__global__ __launch_bounds__(256) void agg2_fused(
        const int* __restrict__ row_ptr, const int* __restrict__ csr_src,
        const unsigned short* __restrict__ h2b, const float* __restrict__ dis,
        const float* __restrict__ b2, float* __restrict__ out, int N) {
    int tid = blockIdx.x * blockDim.x + threadIdx.x;
    int n = tid >> 6;
    int lane = tid & 63;
    if (n >= N) return;
    int j = lane >> 4;
    int c = lane & 15;
    int beg = row_ptr[n];
    int end = row_ptr[n + 1];
    float acc = 0.f;
    for (int i = beg + j; i < end; i += 4) {
        int s = csr_src[i];
        acc += bf2f(h2b[(size_t)s * NCLS + c]);
    }
    acc += __shfl_xor(acc, 16, 64);
    acc += __shfl_xor(acc, 32, 64);
    if (j == 0) out[(size_t)n * NCLS + c] = dis[n] * acc + b2[c];
}

extern "C" void kernel_launch(void* const* d_in, const int* in_sizes, int n_in,
                              void* d_out, int out_size, void* d_ws, size_t ws_size,
                              hipStream_t stream) {
    const float* x   = (const float*)d_in[0];
    const int*   src = (const int*)  d_in[1];
    const int*   dst = (const int*)  d_in[2];
    const float* W1  = (const float*)d_in[3];
    const float* b1  = (const float*)d_in[4];
    const float* W2  = (const float*)d_in[5];
    const float* b2  = (const float*)d_in[6];
    float* out = (float*)d_out;
    int E = in_sizes[1];
    int N = in_sizes[0] / F_IN;
    int NB = (N + BNODES - 1) >> BSHIFT;
    int nchunks = (E + CHUNK - 1) / CHUNK;

    char* ws = (char*)d_ws;
    size_t off = 0;
    auto alloc = [&](size_t bytes) { size_t o = off; off = (off + bytes + 255) & ~(size_t)255; return (void*)(ws + o); };
    int*   bucket_count  = (int*)  alloc((size_t)NB * 4);
    int*   bucket_base   = (int*)  alloc((size_t)(NB + 1) * 4);
    int*   bucket_cursor = (int*)  alloc((size_t)NB * 4);
    int*   row_ptr       = (int*)  alloc((size_t)(N + 1) * 4);
    int*   csr_src       = (int*)  alloc((size_t)E * 4);
    float* dis           = (float*)alloc((size_t)N * 4);
    unsigned short* h1b  = (unsigned short*)alloc((size_t)N * HID * 2);
    unsigned short* h2b  = (unsigned short*)alloc((size_t)N * NCLS * 2);
    // part[] aliases h1b: dead before gemm1 writes h1b (E*4 = 6.8MB <= N*HID*2 = 12.8MB)
    unsigned int* part   = (unsigned int*)h1b;

    hipMemsetAsync(bucket_count, 0, (size_t)NB * 4, stream);

    hist_kernel   <<<nchunks, 256, 0, stream>>>(dst, bucket_count, E, NB);
    scan_buckets  <<<1, 512, 0, stream>>>(bucket_count, bucket_base, bucket_cursor, row_ptr, NB, N, E);
    scatter_kernel<<<nchunks, 256, 0, stream>>>(src, dst, bucket_cursor, part, E, NB);
    csr_build     <<<NB, 256, 0, stream>>>(part, bucket_base, csr_src, row_ptr, dis, N);
    gemm1_kernel  <<<(N + 63) / 64, 256, 0, stream>>>(x, W1, dis, h1b, N);
    agg1_fused    <<<(N + 3) / 4, 256, 0, stream>>>(row_ptr, csr_src, h1b, dis, b1, W2, h2b, N);
    agg2_fused    <<<(N + 3) / 4, 256, 0, stream>>>(row_ptr, csr_src, h2b, dis, b2, out, N);
}

// Round 9
// 292.806 us; speedup vs baseline: 1.3297x; 1.3297x over previous
//
#include <hip/hip_runtime.h>

#define F_IN 128
#define HID  64
#define NCLS 16

#define BSHIFT 8            // 256 nodes per bucket
#define BNODES 256
#define NB_MAX 512          // max buckets (N<=128k)
#define CHUNK  8192         // edges per scatter block
#define CAP    8192         // max edges per bucket in LDS (mean 4352, 50+ sigma margin)

typedef __attribute__((ext_vector_type(8))) short bf16x8;
typedef __attribute__((ext_vector_type(4))) float f32x4;

// round-to-nearest-even fp32 -> bf16
__device__ __forceinline__ unsigned short f2bf(float f) {
    unsigned int u = __float_as_uint(f);
    u += 0x7FFFu + ((u >> 16) & 1u);
    return (unsigned short)(u >> 16);
}
__device__ __forceinline__ float bf2f(unsigned short h) {
    return __uint_as_float((unsigned int)h << 16);
}

// ---------- pass 1: global bucket histogram ----------
__global__ __launch_bounds__(256) void hist_kernel(const int* __restrict__ dst,
                                                   int* __restrict__ bucket_count,
                                                   int E, int NB) {
    __shared__ int hist[NB_MAX];
    int tid = threadIdx.x;
    for (int i = tid; i < NB; i += 256) hist[i] = 0;
    __syncthreads();
    int cb = blockIdx.x * CHUNK;
    for (int k = 0; k < CHUNK / 256; k++) {
        int e = cb + k * 256 + tid;
        if (e < E) atomicAdd(&hist[dst[e] >> BSHIFT], 1);
    }
    __syncthreads();
    for (int i = tid; i < NB; i += 256)
        if (hist[i]) atomicAdd(&bucket_count[i], hist[i]);
}

// ---------- pass 2: single-block scan of bucket counts ----------
__global__ __launch_bounds__(512) void scan_buckets(const int* __restrict__ bucket_count,
                                                    int* __restrict__ bucket_base,
                                                    int* __restrict__ bucket_cursor,
                                                    int* __restrict__ row_ptr,
                                                    int NB, int N, int E) {
    __shared__ int s[512];
    int tid = threadIdx.x;
    int v = (tid < NB) ? bucket_count[tid] : 0;
    s[tid] = v;
    __syncthreads();
    for (int off = 1; off < 512; off <<= 1) {
        int t = (tid >= off) ? s[tid - off] : 0;
        __syncthreads();
        s[tid] += t;
        __syncthreads();
    }
    if (tid < NB) {
        int excl = s[tid] - v;
        bucket_base[tid]   = excl;
        bucket_cursor[tid] = excl;
    }
    if (tid == 0) { bucket_base[NB] = E; row_ptr[N] = E; }
}

// ---------- pass 3: partition edges into bucket regions ----------
__global__ __launch_bounds__(256) void scatter_kernel(const int* __restrict__ src,
                                                      const int* __restrict__ dst,
                                                      int* __restrict__ bucket_cursor,
                                                      unsigned int* __restrict__ part,
                                                      int E, int NB) {
    __shared__ int hist[NB_MAX];
    __shared__ int base_s[NB_MAX];
    int tid = threadIdx.x;
    for (int i = tid; i < NB; i += 256) hist[i] = 0;
    __syncthreads();
    int cb = blockIdx.x * CHUNK;
    for (int k = 0; k < CHUNK / 256; k++) {
        int e = cb + k * 256 + tid;
        if (e < E) atomicAdd(&hist[dst[e] >> BSHIFT], 1);
    }
    __syncthreads();
    for (int i = tid; i < NB; i += 256) {
        int c = hist[i];
        base_s[i] = c ? atomicAdd(&bucket_cursor[i], c) : 0;
        hist[i] = 0;
    }
    __syncthreads();
    for (int k = 0; k < CHUNK / 256; k++) {
        int e = cb + k * 256 + tid;
        if (e < E) {
            int d = dst[e];
            int b = d >> BSHIFT;
            int pos = base_s[b] + atomicAdd(&hist[b], 1);
            part[pos] = ((unsigned int)(d & (BNODES - 1)) << 24) | (unsigned int)src[e];
        }
    }
}

// ---------- pass 4: per-bucket counting sort -> csr_src, row_ptr, dis ----------
__global__ __launch_bounds__(256) void csr_build(const unsigned int* __restrict__ part,
                                                 const int* __restrict__ bucket_base,
                                                 int* __restrict__ csr_src,
                                                 int* __restrict__ row_ptr,
                                                 float* __restrict__ dis,
                                                 int N) {
    __shared__ unsigned int eL[CAP];
    __shared__ unsigned int outL[CAP];
    __shared__ int cnt[BNODES];
    __shared__ int sc[BNODES];
    __shared__ int cur[BNODES];
    int tid = threadIdx.x;
    int b = blockIdx.x;
    int eB = bucket_base[b];
    int eN = bucket_base[b + 1] - eB;
    if (eN > CAP) eN = CAP;

    cnt[tid] = 0;
    __syncthreads();
    for (int i = tid; i < eN; i += 256) {
        unsigned int v = part[eB + i];
        eL[i] = v;
        atomicAdd(&cnt[v >> 24], 1);
    }
    __syncthreads();
    int myc = cnt[tid];
    sc[tid] = myc;
    __syncthreads();
    for (int off = 1; off < 256; off <<= 1) {
        int t = (tid >= off) ? sc[tid - off] : 0;
        __syncthreads();
        sc[tid] += t;
        __syncthreads();
    }
    int excl = sc[tid] - myc;
    cur[tid] = excl;
    int gnode = b * BNODES + tid;
    if (gnode < N) {
        row_ptr[gnode] = eB + excl;
        float d = (float)myc;
        dis[gnode] = d > 0.0f ? rsqrtf(fmaxf(d, 1.0f)) : 0.0f;
    }
    __syncthreads();
    for (int i = tid; i < eN; i += 256) {
        unsigned int v = eL[i];
        int pos = atomicAdd(&cur[v >> 24], 1);
        outL[pos] = v & 0xFFFFFFu;
    }
    __syncthreads();
    for (int i = tid; i < eN; i += 256)
        csr_src[eB + i] = (int)outL[i];
}

// ---------- W1 -> bf16, transposed: w1t[n][k] = bf16(W1[k][n]) ----------
__global__ __launch_bounds__(256) void w1t_kernel(const float* __restrict__ W1,
                                                  unsigned short* __restrict__ w1t) {
    int i = blockIdx.x * 256 + threadIdx.x;   // 8192 elems
    int k = i >> 6;
    int n = i & 63;
    w1t[n * F_IN + k] = f2bf(W1[i]);
}

// ---------- gemm1 via MFMA bf16: 64 rows/block, 4 waves x (16 rows x 64 cols) ----------
__global__ __launch_bounds__(256) void gemm1_kernel(
        const float* __restrict__ x, const unsigned short* __restrict__ w1t,
        const float* __restrict__ dis, unsigned short* __restrict__ h1b, int N) {
    __shared__ unsigned short xs[64][136];   // 64 rows x 128 k bf16 (stride 136)
    __shared__ unsigned short wsb[64][136];  // 64 cols x 128 k bf16 (W1 transposed)
    __shared__ float diss[64];
    int tid = threadIdx.x;
    int w = tid >> 6;
    int lane = tid & 63;
    int row0 = blockIdx.x * 64;

    // stage x -> bf16 LDS (2048 float4, coalesced)
    #pragma unroll
    for (int it = 0; it < 8; it++) {
        int f = it * 256 + tid;
        int r = f >> 5, c = f & 31;
        float4 v = make_float4(0.f, 0.f, 0.f, 0.f);
        if (row0 + r < N) v = ((const float4*)x)[(size_t)(row0 + r) * 32 + c];
        unsigned int p0 = (unsigned int)f2bf(v.x) | ((unsigned int)f2bf(v.y) << 16);
        unsigned int p1 = (unsigned int)f2bf(v.z) | ((unsigned int)f2bf(v.w) << 16);
        *(uint2*)&xs[r][c * 4] = make_uint2(p0, p1);
    }
    // stage w1t: 64 rows x 128 bf16 = 16 uint4 per row, 1024 uint4 total
    #pragma unroll
    for (int it = 0; it < 4; it++) {
        int f = it * 256 + tid;          // 0..1023
        int r = f >> 4, c = f & 15;      // FIXED: 16 uint4 per row (was >>3 / &7 -> LDS OOB)
        *(uint4*)&wsb[r][c * 8] = ((const uint4*)w1t)[f];
    }
    if (tid < 64) diss[tid] = (row0 + tid < N) ? dis[row0 + tid] : 0.f;
    __syncthreads();

    int q = lane >> 4;
    int l15 = lane & 15;
    f32x4 acc[4] = {{0,0,0,0},{0,0,0,0},{0,0,0,0},{0,0,0,0}};
    bf16x8 a[4];
    // A frags: A[m = lane&15][k = quad*8+j], rows w*16..w*16+15
    #pragma unroll
    for (int kk = 0; kk < 4; kk++)
        a[kk] = *(const bf16x8*)&xs[w * 16 + l15][kk * 32 + q * 8];
    #pragma unroll
    for (int kk = 0; kk < 4; kk++) {
        #pragma unroll
        for (int ct = 0; ct < 4; ct++) {
            // B frags: B[k = quad*8+j][n = lane&15], cols ct*16..ct*16+15
            bf16x8 b = *(const bf16x8*)&wsb[ct * 16 + l15][kk * 32 + q * 8];
            acc[ct] = __builtin_amdgcn_mfma_f32_16x16x32_bf16(a[kk], b, acc[ct], 0, 0, 0);
        }
    }
    __syncthreads();
    // epilogue: D[row = quad*4+reg][col = lane&15]; scale by dis, park in LDS
    #pragma unroll
    for (int ct = 0; ct < 4; ct++) {
        #pragma unroll
        for (int r = 0; r < 4; r++) {
            int m = w * 16 + q * 4 + r;
            xs[m][ct * 16 + l15] = f2bf(acc[ct][r] * diss[m]);
        }
    }
    __syncthreads();
    // coalesced write-out: 64 rows x 64 cols bf16 = 512 uint4
    #pragma unroll
    for (int it = 0; it < 2; it++) {
        int f = it * 256 + tid;
        int r = f >> 3, c = f & 7;       // 8 uint4 per 64-bf16 row (correct here)
        if (row0 + r < N)
            ((uint4*)&h1b[(size_t)(row0 + r) * HID])[c] = *(const uint4*)&xs[r][c * 8];
    }
}

// ---------- fused layer-1 agg (bf16 gather) + ReLU + W2 GEMM ----------
__global__ __launch_bounds__(256) void agg1_fused(
        const int* __restrict__ row_ptr, const int* __restrict__ csr_src,
        const unsigned short* __restrict__ h1b, const float* __restrict__ dis,
        const float* __restrict__ b1, const float* __restrict__ W2,
        unsigned short* __restrict__ h2b, int N) {
    __shared__ float W2s[HID * NCLS];
    __shared__ float ts[4][HID];
    int tid = threadIdx.x;
    for (int i = tid; i < HID * NCLS; i += 256) W2s[i] = W2[i];
    __syncthreads();

    int w = tid >> 6;
    int lane = tid & 63;
    int n = blockIdx.x * 4 + w;

    float acc = 0.f;
    float dn = 0.f;
    if (n < N) {
        dn = dis[n];
        int beg = row_ptr[n];
        int end = row_ptr[n + 1];
        int i = beg;
        for (; i + 4 <= end; i += 4) {
            int s0 = csr_src[i];
            int s1 = csr_src[i + 1];
            int s2 = csr_src[i + 2];
            int s3 = csr_src[i + 3];
            float v0 = bf2f(h1b[(size_t)s0 * HID + lane]);
            float v1 = bf2f(h1b[(size_t)s1 * HID + lane]);
            float v2 = bf2f(h1b[(size_t)s2 * HID + lane]);
            float v3 = bf2f(h1b[(size_t)s3 * HID + lane]);
            acc += v0 + v1 + v2 + v3;
        }
        for (; i < end; i++)
            acc += bf2f(h1b[(size_t)csr_src[i] * HID + lane]);
    }

    float t = fmaxf(dn * acc + b1[lane], 0.f);
    ts[w][lane] = t;

    int q = lane >> 4;
    int c = lane & 15;
    float p = 0.f;
    #pragma unroll
    for (int jj = 0; jj < 16; jj++) {
        int j = q * 16 + jj;
        p += ts[w][j] * W2s[j * NCLS + c];
    }
    p += __shfl_xor(p, 16, 64);
    p += __shfl_xor(p, 32, 64);
    if (n < N && q == 0) h2b[(size_t)n * NCLS + c] = f2bf(p * dn);
}

// ---------- fused layer-2 agg (bf16 gather) + epilogue ----------
__global__ __launch_bounds__(256) void agg2_fused(
        const int* __restrict__ row_ptr, const int* __restrict__ csr_src,
        const unsigned short* __restrict__ h2b, const float* __restrict__ dis,
        const float* __restrict__ b2, float* __restrict__ out, int N) {
    int tid = blockIdx.x * blockDim.x + threadIdx.x;
    int n = tid >> 6;
    int lane = tid & 63;
    if (n >= N) return;
    int j = lane >> 4;
    int c = lane & 15;
    int beg = row_ptr[n];
    int end = row_ptr[n + 1];
    float acc = 0.f;
    for (int i = beg + j; i < end; i += 4) {
        int s = csr_src[i];
        acc += bf2f(h2b[(size_t)s * NCLS + c]);
    }
    acc += __shfl_xor(acc, 16, 64);
    acc += __shfl_xor(acc, 32, 64);
    if (j == 0) out[(size_t)n * NCLS + c] = dis[n] * acc + b2[c];
}

extern "C" void kernel_launch(void* const* d_in, const int* in_sizes, int n_in,
                              void* d_out, int out_size, void* d_ws, size_t ws_size,
                              hipStream_t stream) {
    const float* x   = (const float*)d_in[0];
    const int*   src = (const int*)  d_in[1];
    const int*   dst = (const int*)  d_in[2];
    const float* W1  = (const float*)d_in[3];
    const float* b1  = (const float*)d_in[4];
    const float* W2  = (const float*)d_in[5];
    const float* b2  = (const float*)d_in[6];
    float* out = (float*)d_out;
    int E = in_sizes[1];
    int N = in_sizes[0] / F_IN;
    int NB = (N + BNODES - 1) >> BSHIFT;
    int nchunks = (E + CHUNK - 1) / CHUNK;

    char* ws = (char*)d_ws;
    size_t off = 0;
    auto alloc = [&](size_t bytes) { size_t o = off; off = (off + bytes + 255) & ~(size_t)255; return (void*)(ws + o); };
    int*   bucket_count  = (int*)  alloc((size_t)NB * 4);
    int*   bucket_base   = (int*)  alloc((size_t)(NB + 1) * 4);
    int*   bucket_cursor = (int*)  alloc((size_t)NB * 4);
    int*   row_ptr       = (int*)  alloc((size_t)(N + 1) * 4);
    int*   csr_src       = (int*)  alloc((size_t)E * 4);
    float* dis           = (float*)alloc((size_t)N * 4);
    unsigned short* w1t  = (unsigned short*)alloc((size_t)F_IN * HID * 2);
    unsigned short* h1b  = (unsigned short*)alloc((size_t)N * HID * 2);
    unsigned short* h2b  = (unsigned short*)alloc((size_t)N * NCLS * 2);
    // part[] aliases h1b: dead before gemm1 writes h1b (E*4 = 6.8MB <= N*HID*2 = 12.8MB)
    unsigned int* part   = (unsigned int*)h1b;

    hipMemsetAsync(bucket_count, 0, (size_t)NB * 4, stream);

    w1t_kernel    <<<(F_IN * HID + 255) / 256, 256, 0, stream>>>(W1, w1t);
    hist_kernel   <<<nchunks, 256, 0, stream>>>(dst, bucket_count, E, NB);
    scan_buckets  <<<1, 512, 0, stream>>>(bucket_count, bucket_base, bucket_cursor, row_ptr, NB, N, E);
    scatter_kernel<<<nchunks, 256, 0, stream>>>(src, dst, bucket_cursor, part, E, NB);
    csr_build     <<<NB, 256, 0, stream>>>(part, bucket_base, csr_src, row_ptr, dis, N);
    gemm1_kernel  <<<(N + 63) / 64, 256, 0, stream>>>(x, w1t, dis, h1b, N);
    agg1_fused    <<<(N + 3) / 4, 256, 0, stream>>>(row_ptr, csr_src, h1b, dis, b1, W2, h2b, N);
    agg2_fused    <<<(N + 3) / 4, 256, 0, stream>>>(row_ptr, csr_src, h2b, dis, b2, out, N);
}

// Round 10
// 271.705 us; speedup vs baseline: 1.4329x; 1.0777x over previous
//
#include <hip/hip_runtime.h>

#define F_IN 128
#define HID  64
#define NCLS 16

#define BSHIFT 8            // 256 nodes per bucket
#define BNODES 256
#define NB_MAX 512          // max buckets (N<=128k)
#define CHUNK  8192         // edges per scatter block
#define CAP    8192         // max edges per bucket in LDS (mean 4352, 50+ sigma margin)

typedef __attribute__((ext_vector_type(8))) short bf16x8;
typedef __attribute__((ext_vector_type(4))) float f32x4;

// round-to-nearest-even fp32 -> bf16
__device__ __forceinline__ unsigned short f2bf(float f) {
    unsigned int u = __float_as_uint(f);
    u += 0x7FFFu + ((u >> 16) & 1u);
    return (unsigned short)(u >> 16);
}
__device__ __forceinline__ float bf2f(unsigned short h) {
    return __uint_as_float((unsigned int)h << 16);
}
__device__ __forceinline__ float bflo(unsigned int u) {
    return __uint_as_float(u << 16);
}
__device__ __forceinline__ float bfhi(unsigned int u) {
    return __uint_as_float(u & 0xFFFF0000u);
}

// ---------- pass 1: global bucket histogram ----------
__global__ __launch_bounds__(256) void hist_kernel(const int* __restrict__ dst,
                                                   int* __restrict__ bucket_count,
                                                   int E, int NB) {
    __shared__ int hist[NB_MAX];
    int tid = threadIdx.x;
    for (int i = tid; i < NB; i += 256) hist[i] = 0;
    __syncthreads();
    int cb = blockIdx.x * CHUNK;
    for (int k = 0; k < CHUNK / 256; k++) {
        int e = cb + k * 256 + tid;
        if (e < E) atomicAdd(&hist[dst[e] >> BSHIFT], 1);
    }
    __syncthreads();
    for (int i = tid; i < NB; i += 256)
        if (hist[i]) atomicAdd(&bucket_count[i], hist[i]);
}

// ---------- pass 2: single-block scan of bucket counts ----------
__global__ __launch_bounds__(512) void scan_buckets(const int* __restrict__ bucket_count,
                                                    int* __restrict__ bucket_base,
                                                    int* __restrict__ bucket_cursor,
                                                    int* __restrict__ row_ptr,
                                                    int NB, int N, int E) {
    __shared__ int s[512];
    int tid = threadIdx.x;
    int v = (tid < NB) ? bucket_count[tid] : 0;
    s[tid] = v;
    __syncthreads();
    for (int off = 1; off < 512; off <<= 1) {
        int t = (tid >= off) ? s[tid - off] : 0;
        __syncthreads();
        s[tid] += t;
        __syncthreads();
    }
    if (tid < NB) {
        int excl = s[tid] - v;
        bucket_base[tid]   = excl;
        bucket_cursor[tid] = excl;
    }
    if (tid == 0) { bucket_base[NB] = E; row_ptr[N] = E; }
}

// ---------- pass 3: partition edges into bucket regions ----------
__global__ __launch_bounds__(256) void scatter_kernel(const int* __restrict__ src,
                                                      const int* __restrict__ dst,
                                                      int* __restrict__ bucket_cursor,
                                                      unsigned int* __restrict__ part,
                                                      int E, int NB) {
    __shared__ int hist[NB_MAX];
    __shared__ int base_s[NB_MAX];
    int tid = threadIdx.x;
    for (int i = tid; i < NB; i += 256) hist[i] = 0;
    __syncthreads();
    int cb = blockIdx.x * CHUNK;
    for (int k = 0; k < CHUNK / 256; k++) {
        int e = cb + k * 256 + tid;
        if (e < E) atomicAdd(&hist[dst[e] >> BSHIFT], 1);
    }
    __syncthreads();
    for (int i = tid; i < NB; i += 256) {
        int c = hist[i];
        base_s[i] = c ? atomicAdd(&bucket_cursor[i], c) : 0;
        hist[i] = 0;
    }
    __syncthreads();
    for (int k = 0; k < CHUNK / 256; k++) {
        int e = cb + k * 256 + tid;
        if (e < E) {
            int d = dst[e];
            int b = d >> BSHIFT;
            int pos = base_s[b] + atomicAdd(&hist[b], 1);
            part[pos] = ((unsigned int)(d & (BNODES - 1)) << 24) | (unsigned int)src[e];
        }
    }
}

// ---------- pass 4: per-bucket counting sort -> csr_src, row_ptr, dis ----------
__global__ __launch_bounds__(256) void csr_build(const unsigned int* __restrict__ part,
                                                 const int* __restrict__ bucket_base,
                                                 int* __restrict__ csr_src,
                                                 int* __restrict__ row_ptr,
                                                 float* __restrict__ dis,
                                                 int N) {
    __shared__ unsigned int eL[CAP];
    __shared__ unsigned int outL[CAP];
    __shared__ int cnt[BNODES];
    __shared__ int sc[BNODES];
    __shared__ int cur[BNODES];
    int tid = threadIdx.x;
    int b = blockIdx.x;
    int eB = bucket_base[b];
    int eN = bucket_base[b + 1] - eB;
    if (eN > CAP) eN = CAP;

    cnt[tid] = 0;
    __syncthreads();
    for (int i = tid; i < eN; i += 256) {
        unsigned int v = part[eB + i];
        eL[i] = v;
        atomicAdd(&cnt[v >> 24], 1);
    }
    __syncthreads();
    int myc = cnt[tid];
    sc[tid] = myc;
    __syncthreads();
    for (int off = 1; off < 256; off <<= 1) {
        int t = (tid >= off) ? sc[tid - off] : 0;
        __syncthreads();
        sc[tid] += t;
        __syncthreads();
    }
    int excl = sc[tid] - myc;
    cur[tid] = excl;
    int gnode = b * BNODES + tid;
    if (gnode < N) {
        row_ptr[gnode] = eB + excl;
        float d = (float)myc;
        dis[gnode] = d > 0.0f ? rsqrtf(fmaxf(d, 1.0f)) : 0.0f;
    }
    __syncthreads();
    for (int i = tid; i < eN; i += 256) {
        unsigned int v = eL[i];
        int pos = atomicAdd(&cur[v >> 24], 1);
        outL[pos] = v & 0xFFFFFFu;
    }
    __syncthreads();
    for (int i = tid; i < eN; i += 256)
        csr_src[eB + i] = (int)outL[i];
}

// ---------- W1 -> bf16, transposed: w1t[n][k] = bf16(W1[k][n]) ----------
__global__ __launch_bounds__(256) void w1t_kernel(const float* __restrict__ W1,
                                                  unsigned short* __restrict__ w1t) {
    int i = blockIdx.x * 256 + threadIdx.x;   // 8192 elems
    int k = i >> 6;
    int n = i & 63;
    w1t[n * F_IN + k] = f2bf(W1[i]);
}

// ---------- gemm1 via MFMA bf16: 64 rows/block, 4 waves x (16 rows x 64 cols) ----------
__global__ __launch_bounds__(256) void gemm1_kernel(
        const float* __restrict__ x, const unsigned short* __restrict__ w1t,
        const float* __restrict__ dis, unsigned short* __restrict__ h1b, int N) {
    __shared__ unsigned short xs[64][136];   // 64 rows x 128 k bf16 (stride 136)
    __shared__ unsigned short wsb[64][136];  // 64 cols x 128 k bf16 (W1 transposed)
    __shared__ float diss[64];
    int tid = threadIdx.x;
    int w = tid >> 6;
    int lane = tid & 63;
    int row0 = blockIdx.x * 64;

    // stage x -> bf16 LDS (2048 float4, coalesced)
    #pragma unroll
    for (int it = 0; it < 8; it++) {
        int f = it * 256 + tid;
        int r = f >> 5, c = f & 31;
        float4 v = make_float4(0.f, 0.f, 0.f, 0.f);
        if (row0 + r < N) v = ((const float4*)x)[(size_t)(row0 + r) * 32 + c];
        unsigned int p0 = (unsigned int)f2bf(v.x) | ((unsigned int)f2bf(v.y) << 16);
        unsigned int p1 = (unsigned int)f2bf(v.z) | ((unsigned int)f2bf(v.w) << 16);
        *(uint2*)&xs[r][c * 4] = make_uint2(p0, p1);
    }
    // stage w1t: 64 rows x 128 bf16 = 16 uint4 per row, 1024 uint4 total
    #pragma unroll
    for (int it = 0; it < 4; it++) {
        int f = it * 256 + tid;          // 0..1023
        int r = f >> 4, c = f & 15;      // 16 uint4 per row
        *(uint4*)&wsb[r][c * 8] = ((const uint4*)w1t)[f];
    }
    if (tid < 64) diss[tid] = (row0 + tid < N) ? dis[row0 + tid] : 0.f;
    __syncthreads();

    int q = lane >> 4;
    int l15 = lane & 15;
    f32x4 acc[4] = {{0,0,0,0},{0,0,0,0},{0,0,0,0},{0,0,0,0}};
    bf16x8 a[4];
    // A frags: A[m = lane&15][k = quad*8+j], rows w*16..w*16+15
    #pragma unroll
    for (int kk = 0; kk < 4; kk++)
        a[kk] = *(const bf16x8*)&xs[w * 16 + l15][kk * 32 + q * 8];
    #pragma unroll
    for (int kk = 0; kk < 4; kk++) {
        #pragma unroll
        for (int ct = 0; ct < 4; ct++) {
            // B frags: B[k = quad*8+j][n = lane&15], cols ct*16..ct*16+15
            bf16x8 b = *(const bf16x8*)&wsb[ct * 16 + l15][kk * 32 + q * 8];
            acc[ct] = __builtin_amdgcn_mfma_f32_16x16x32_bf16(a[kk], b, acc[ct], 0, 0, 0);
        }
    }
    __syncthreads();
    // epilogue: D[row = quad*4+reg][col = lane&15]; scale by dis, park in LDS
    #pragma unroll
    for (int ct = 0; ct < 4; ct++) {
        #pragma unroll
        for (int r = 0; r < 4; r++) {
            int m = w * 16 + q * 4 + r;
            xs[m][ct * 16 + l15] = f2bf(acc[ct][r] * diss[m]);
        }
    }
    __syncthreads();
    // coalesced write-out: 64 rows x 64 cols bf16 = 512 uint4
    #pragma unroll
    for (int it = 0; it < 2; it++) {
        int f = it * 256 + tid;
        int r = f >> 3, c = f & 7;       // 8 uint4 per 64-bf16 row
        if (row0 + r < N)
            ((uint4*)&h1b[(size_t)(row0 + r) * HID])[c] = *(const uint4*)&xs[r][c * 8];
    }
}

// ---------- fused layer-1 agg + ReLU + W2 GEMM ----------
// gather: 4 edge slots x 16 dim-quads, uint2 (4 bf16) per lane -> 4 edges/instr
__global__ __launch_bounds__(256) void agg1_fused(
        const int* __restrict__ row_ptr, const int* __restrict__ csr_src,
        const unsigned short* __restrict__ h1b, const float* __restrict__ dis,
        const float* __restrict__ b1, const float* __restrict__ W2,
        unsigned short* __restrict__ h2b, int N) {
    __shared__ float W2s[HID * NCLS];
    __shared__ float ts[4][HID];
    int tid = threadIdx.x;
    for (int i = tid; i < HID * NCLS; i += 256) W2s[i] = W2[i];
    __syncthreads();

    int w = tid >> 6;
    int lane = tid & 63;
    int n = blockIdx.x * 4 + w;
    int slot = lane >> 4;    // edge slot 0..3
    int p = lane & 15;       // dim-quad: dims p*4..p*4+3

    float a0 = 0.f, a1 = 0.f, a2 = 0.f, a3 = 0.f;
    float dn = 0.f;
    if (n < N) {
        dn = dis[n];
        int beg = row_ptr[n];
        int end = row_ptr[n + 1];
        for (int i = beg + slot; i < end; i += 4) {
            int s = csr_src[i];
            uint2 v = *(const uint2*)&h1b[(size_t)s * HID + p * 4];
            a0 += bflo(v.x);
            a1 += bfhi(v.x);
            a2 += bflo(v.y);
            a3 += bfhi(v.y);
        }
    }
    // reduce across the 4 edge slots
    a0 += __shfl_xor(a0, 16, 64); a0 += __shfl_xor(a0, 32, 64);
    a1 += __shfl_xor(a1, 16, 64); a1 += __shfl_xor(a1, 32, 64);
    a2 += __shfl_xor(a2, 16, 64); a2 += __shfl_xor(a2, 32, 64);
    a3 += __shfl_xor(a3, 16, 64); a3 += __shfl_xor(a3, 32, 64);

    if (n < N && slot == 0) {
        ts[w][p * 4 + 0] = fmaxf(dn * a0 + b1[p * 4 + 0], 0.f);
        ts[w][p * 4 + 1] = fmaxf(dn * a1 + b1[p * 4 + 1], 0.f);
        ts[w][p * 4 + 2] = fmaxf(dn * a2 + b1[p * 4 + 2], 0.f);
        ts[w][p * 4 + 3] = fmaxf(dn * a3 + b1[p * 4 + 3], 0.f);
    }
    // wave-local LDS round-trip (same wave writes+reads; compiler inserts lgkmcnt)
    int q = lane >> 4;
    int c = lane & 15;
    float pacc = 0.f;
    #pragma unroll
    for (int jj = 0; jj < 16; jj++) {
        int j = q * 16 + jj;
        pacc += ts[w][j] * W2s[j * NCLS + c];
    }
    pacc += __shfl_xor(pacc, 16, 64);
    pacc += __shfl_xor(pacc, 32, 64);
    if (n < N && q == 0) h2b[(size_t)n * NCLS + c] = f2bf(pacc * dn);
}

// ---------- fused layer-2 agg + epilogue ----------
// gather: 16 edge slots x 4 cls-quads, uint2 per lane -> 16 edges/instr
__global__ __launch_bounds__(256) void agg2_fused(
        const int* __restrict__ row_ptr, const int* __restrict__ csr_src,
        const unsigned short* __restrict__ h2b, const float* __restrict__ dis,
        const float* __restrict__ b2, float* __restrict__ out, int N) {
    int tid = blockIdx.x * blockDim.x + threadIdx.x;
    int n = tid >> 6;        // wave-uniform
    int lane = tid & 63;
    if (n >= N) return;      // wave-uniform exit
    int slot = lane >> 2;    // edge slot 0..15
    int p = lane & 3;        // cls-quad: classes p*4..p*4+3

    float a0 = 0.f, a1 = 0.f, a2 = 0.f, a3 = 0.f;
    int beg = row_ptr[n];
    int end = row_ptr[n + 1];
    for (int i = beg + slot; i < end; i += 16) {
        int s = csr_src[i];
        uint2 v = *(const uint2*)&h2b[(size_t)s * NCLS + p * 4];
        a0 += bflo(v.x);
        a1 += bfhi(v.x);
        a2 += bflo(v.y);
        a3 += bfhi(v.y);
    }
    #pragma unroll
    for (int m = 4; m <= 32; m <<= 1) {
        a0 += __shfl_xor(a0, m, 64);
        a1 += __shfl_xor(a1, m, 64);
        a2 += __shfl_xor(a2, m, 64);
        a3 += __shfl_xor(a3, m, 64);
    }
    if (lane < 4) {
        float dn = dis[n];
        float4 o = make_float4(dn * a0 + b2[p * 4 + 0], dn * a1 + b2[p * 4 + 1],
                               dn * a2 + b2[p * 4 + 2], dn * a3 + b2[p * 4 + 3]);
        *(float4*)&out[(size_t)n * NCLS + p * 4] = o;
    }
}

extern "C" void kernel_launch(void* const* d_in, const int* in_sizes, int n_in,
                              void* d_out, int out_size, void* d_ws, size_t ws_size,
                              hipStream_t stream) {
    const float* x   = (const float*)d_in[0];
    const int*   src = (const int*)  d_in[1];
    const int*   dst = (const int*)  d_in[2];
    const float* W1  = (const float*)d_in[3];
    const float* b1  = (const float*)d_in[4];
    const float* W2  = (const float*)d_in[5];
    const float* b2  = (const float*)d_in[6];
    float* out = (float*)d_out;
    int E = in_sizes[1];
    int N = in_sizes[0] / F_IN;
    int NB = (N + BNODES - 1) >> BSHIFT;
    int nchunks = (E + CHUNK - 1) / CHUNK;

    char* ws = (char*)d_ws;
    size_t off = 0;
    auto alloc = [&](size_t bytes) { size_t o = off; off = (off + bytes + 255) & ~(size_t)255; return (void*)(ws + o); };
    int*   bucket_count  = (int*)  alloc((size_t)NB * 4);
    int*   bucket_base   = (int*)  alloc((size_t)(NB + 1) * 4);
    int*   bucket_cursor = (int*)  alloc((size_t)NB * 4);
    int*   row_ptr       = (int*)  alloc((size_t)(N + 1) * 4);
    int*   csr_src       = (int*)  alloc((size_t)E * 4);
    float* dis           = (float*)alloc((size_t)N * 4);
    unsigned short* w1t  = (unsigned short*)alloc((size_t)F_IN * HID * 2);
    unsigned short* h1b  = (unsigned short*)alloc((size_t)N * HID * 2);
    unsigned short* h2b  = (unsigned short*)alloc((size_t)N * NCLS * 2);
    // part[] aliases h1b: dead before gemm1 writes h1b (E*4 = 6.8MB <= N*HID*2 = 12.8MB)
    unsigned int* part   = (unsigned int*)h1b;

    hipMemsetAsync(bucket_count, 0, (size_t)NB * 4, stream);

    w1t_kernel    <<<(F_IN * HID + 255) / 256, 256, 0, stream>>>(W1, w1t);
    hist_kernel   <<<nchunks, 256, 0, stream>>>(dst, bucket_count, E, NB);
    scan_buckets  <<<1, 512, 0, stream>>>(bucket_count, bucket_base, bucket_cursor, row_ptr, NB, N, E);
    scatter_kernel<<<nchunks, 256, 0, stream>>>(src, dst, bucket_cursor, part, E, NB);
    csr_build     <<<NB, 256, 0, stream>>>(part, bucket_base, csr_src, row_ptr, dis, N);
    gemm1_kernel  <<<(N + 63) / 64, 256, 0, stream>>>(x, w1t, dis, h1b, N);
    agg1_fused    <<<(N + 3) / 4, 256, 0, stream>>>(row_ptr, csr_src, h1b, dis, b1, W2, h2b, N);
    agg2_fused    <<<(N + 3) / 4, 256, 0, stream>>>(row_ptr, csr_src, h2b, dis, b2, out, N);
}

// Round 11
// 266.759 us; speedup vs baseline: 1.4595x; 1.0185x over previous
//
#include <hip/hip_runtime.h>

#define F_IN 128
#define HID  64
#define NCLS 16

#define BSHIFT 8            // 256 nodes per bucket
#define BNODES 256
#define NB_MAX 512          // max buckets (N<=128k)
#define CHUNK  8192         // edges per scatter block
#define CAP    8192         // max edges per bucket in LDS (mean 4352, 50+ sigma margin)

typedef __attribute__((ext_vector_type(8))) short bf16x8;
typedef __attribute__((ext_vector_type(4))) float f32x4;

// round-to-nearest-even fp32 -> bf16
__device__ __forceinline__ unsigned short f2bf(float f) {
    unsigned int u = __float_as_uint(f);
    u += 0x7FFFu + ((u >> 16) & 1u);
    return (unsigned short)(u >> 16);
}
__device__ __forceinline__ float bf2f(unsigned short h) {
    return __uint_as_float((unsigned int)h << 16);
}
__device__ __forceinline__ float bflo(unsigned int u) {
    return __uint_as_float(u << 16);
}
__device__ __forceinline__ float bfhi(unsigned int u) {
    return __uint_as_float(u & 0xFFFF0000u);
}

// ---------- pass 1: global bucket histogram ----------
__global__ __launch_bounds__(256) void hist_kernel(const int* __restrict__ dst,
                                                   int* __restrict__ bucket_count,
                                                   int E, int NB) {
    __shared__ int hist[NB_MAX];
    int tid = threadIdx.x;
    for (int i = tid; i < NB; i += 256) hist[i] = 0;
    __syncthreads();
    int cb = blockIdx.x * CHUNK;
    for (int k = 0; k < CHUNK / 256; k++) {
        int e = cb + k * 256 + tid;
        if (e < E) atomicAdd(&hist[dst[e] >> BSHIFT], 1);
    }
    __syncthreads();
    for (int i = tid; i < NB; i += 256)
        if (hist[i]) atomicAdd(&bucket_count[i], hist[i]);
}

// ---------- pass 2: single-block scan of bucket counts ----------
__global__ __launch_bounds__(512) void scan_buckets(const int* __restrict__ bucket_count,
                                                    int* __restrict__ bucket_base,
                                                    int* __restrict__ bucket_cursor,
                                                    int* __restrict__ row_ptr,
                                                    int NB, int N, int E) {
    __shared__ int s[512];
    int tid = threadIdx.x;
    int v = (tid < NB) ? bucket_count[tid] : 0;
    s[tid] = v;
    __syncthreads();
    for (int off = 1; off < 512; off <<= 1) {
        int t = (tid >= off) ? s[tid - off] : 0;
        __syncthreads();
        s[tid] += t;
        __syncthreads();
    }
    if (tid < NB) {
        int excl = s[tid] - v;
        bucket_base[tid]   = excl;
        bucket_cursor[tid] = excl;
    }
    if (tid == 0) { bucket_base[NB] = E; row_ptr[N] = E; }
}

// ---------- pass 3: partition edges into bucket regions ----------
__global__ __launch_bounds__(256) void scatter_kernel(const int* __restrict__ src,
                                                      const int* __restrict__ dst,
                                                      int* __restrict__ bucket_cursor,
                                                      unsigned int* __restrict__ part,
                                                      int E, int NB) {
    __shared__ int hist[NB_MAX];
    __shared__ int base_s[NB_MAX];
    int tid = threadIdx.x;
    for (int i = tid; i < NB; i += 256) hist[i] = 0;
    __syncthreads();
    int cb = blockIdx.x * CHUNK;
    for (int k = 0; k < CHUNK / 256; k++) {
        int e = cb + k * 256 + tid;
        if (e < E) atomicAdd(&hist[dst[e] >> BSHIFT], 1);
    }
    __syncthreads();
    for (int i = tid; i < NB; i += 256) {
        int c = hist[i];
        base_s[i] = c ? atomicAdd(&bucket_cursor[i], c) : 0;
        hist[i] = 0;
    }
    __syncthreads();
    for (int k = 0; k < CHUNK / 256; k++) {
        int e = cb + k * 256 + tid;
        if (e < E) {
            int d = dst[e];
            int b = d >> BSHIFT;
            int pos = base_s[b] + atomicAdd(&hist[b], 1);
            part[pos] = ((unsigned int)(d & (BNODES - 1)) << 24) | (unsigned int)src[e];
        }
    }
}

// ---------- pass 4: per-bucket counting sort -> csr_src, row_ptr, dis ----------
__global__ __launch_bounds__(256) void csr_build(const unsigned int* __restrict__ part,
                                                 const int* __restrict__ bucket_base,
                                                 int* __restrict__ csr_src,
                                                 int* __restrict__ row_ptr,
                                                 float* __restrict__ dis,
                                                 int N) {
    __shared__ unsigned int eL[CAP];
    __shared__ unsigned int outL[CAP];
    __shared__ int cnt[BNODES];
    __shared__ int sc[BNODES];
    __shared__ int cur[BNODES];
    int tid = threadIdx.x;
    int b = blockIdx.x;
    int eB = bucket_base[b];
    int eN = bucket_base[b + 1] - eB;
    if (eN > CAP) eN = CAP;

    cnt[tid] = 0;
    __syncthreads();
    for (int i = tid; i < eN; i += 256) {
        unsigned int v = part[eB + i];
        eL[i] = v;
        atomicAdd(&cnt[v >> 24], 1);
    }
    __syncthreads();
    int myc = cnt[tid];
    sc[tid] = myc;
    __syncthreads();
    for (int off = 1; off < 256; off <<= 1) {
        int t = (tid >= off) ? sc[tid - off] : 0;
        __syncthreads();
        sc[tid] += t;
        __syncthreads();
    }
    int excl = sc[tid] - myc;
    cur[tid] = excl;
    int gnode = b * BNODES + tid;
    if (gnode < N) {
        row_ptr[gnode] = eB + excl;
        float d = (float)myc;
        dis[gnode] = d > 0.0f ? rsqrtf(fmaxf(d, 1.0f)) : 0.0f;
    }
    __syncthreads();
    for (int i = tid; i < eN; i += 256) {
        unsigned int v = eL[i];
        int pos = atomicAdd(&cur[v >> 24], 1);
        outL[pos] = v & 0xFFFFFFu;
    }
    __syncthreads();
    for (int i = tid; i < eN; i += 256)
        csr_src[eB + i] = (int)outL[i];
}

// ---------- W1 -> bf16, transposed: w1t[n][k] = bf16(W1[k][n]) ----------
__global__ __launch_bounds__(256) void w1t_kernel(const float* __restrict__ W1,
                                                  unsigned short* __restrict__ w1t) {
    int i = blockIdx.x * 256 + threadIdx.x;   // 8192 elems
    int k = i >> 6;
    int n = i & 63;
    w1t[n * F_IN + k] = f2bf(W1[i]);
}

// ---------- gemm1 via MFMA bf16: 64 rows/block, 4 waves x (16 rows x 64 cols) ----------
__global__ __launch_bounds__(256) void gemm1_kernel(
        const float* __restrict__ x, const unsigned short* __restrict__ w1t,
        const float* __restrict__ dis, unsigned short* __restrict__ h1b, int N) {
    __shared__ unsigned short xs[64][136];   // 64 rows x 128 k bf16 (stride 136)
    __shared__ unsigned short wsb[64][136];  // 64 cols x 128 k bf16 (W1 transposed)
    __shared__ float diss[64];
    int tid = threadIdx.x;
    int w = tid >> 6;
    int lane = tid & 63;
    int row0 = blockIdx.x * 64;

    // stage x -> bf16 LDS (2048 float4, coalesced)
    #pragma unroll
    for (int it = 0; it < 8; it++) {
        int f = it * 256 + tid;
        int r = f >> 5, c = f & 31;
        float4 v = make_float4(0.f, 0.f, 0.f, 0.f);
        if (row0 + r < N) v = ((const float4*)x)[(size_t)(row0 + r) * 32 + c];
        unsigned int p0 = (unsigned int)f2bf(v.x) | ((unsigned int)f2bf(v.y) << 16);
        unsigned int p1 = (unsigned int)f2bf(v.z) | ((unsigned int)f2bf(v.w) << 16);
        *(uint2*)&xs[r][c * 4] = make_uint2(p0, p1);
    }
    // stage w1t: 64 rows x 128 bf16 = 16 uint4 per row, 1024 uint4 total
    #pragma unroll
    for (int it = 0; it < 4; it++) {
        int f = it * 256 + tid;          // 0..1023
        int r = f >> 4, c = f & 15;      // 16 uint4 per row
        *(uint4*)&wsb[r][c * 8] = ((const uint4*)w1t)[f];
    }
    if (tid < 64) diss[tid] = (row0 + tid < N) ? dis[row0 + tid] : 0.f;
    __syncthreads();

    int q = lane >> 4;
    int l15 = lane & 15;
    f32x4 acc[4] = {{0,0,0,0},{0,0,0,0},{0,0,0,0},{0,0,0,0}};
    bf16x8 a[4];
    // A frags: A[m = lane&15][k = quad*8+j], rows w*16..w*16+15
    #pragma unroll
    for (int kk = 0; kk < 4; kk++)
        a[kk] = *(const bf16x8*)&xs[w * 16 + l15][kk * 32 + q * 8];
    #pragma unroll
    for (int kk = 0; kk < 4; kk++) {
        #pragma unroll
        for (int ct = 0; ct < 4; ct++) {
            // B frags: B[k = quad*8+j][n = lane&15], cols ct*16..ct*16+15
            bf16x8 b = *(const bf16x8*)&wsb[ct * 16 + l15][kk * 32 + q * 8];
            acc[ct] = __builtin_amdgcn_mfma_f32_16x16x32_bf16(a[kk], b, acc[ct], 0, 0, 0);
        }
    }
    __syncthreads();
    // epilogue: D[row = quad*4+reg][col = lane&15]; scale by dis, park in LDS
    #pragma unroll
    for (int ct = 0; ct < 4; ct++) {
        #pragma unroll
        for (int r = 0; r < 4; r++) {
            int m = w * 16 + q * 4 + r;
            xs[m][ct * 16 + l15] = f2bf(acc[ct][r] * diss[m]);
        }
    }
    __syncthreads();
    // coalesced write-out: 64 rows x 64 cols bf16 = 512 uint4
    #pragma unroll
    for (int it = 0; it < 2; it++) {
        int f = it * 256 + tid;
        int r = f >> 3, c = f & 7;       // 8 uint4 per 64-bf16 row
        if (row0 + r < N)
            ((uint4*)&h1b[(size_t)(row0 + r) * HID])[c] = *(const uint4*)&xs[r][c * 8];
    }
}

// ---------- fused layer-1 agg + ReLU + W2 GEMM ----------
// gather: 4 edge slots x 16 dim-quads, uint2 per lane; 4-deep batched gathers for MLP
__global__ __launch_bounds__(256) void agg1_fused(
        const int* __restrict__ row_ptr, const int* __restrict__ csr_src,
        const unsigned short* __restrict__ h1b, const float* __restrict__ dis,
        const float* __restrict__ b1, const float* __restrict__ W2,
        unsigned short* __restrict__ h2b, int N) {
    __shared__ float W2s[HID][NCLS + 1];   // stride 17: kills 4-way bank conflict
    __shared__ float ts[4][HID];
    int tid = threadIdx.x;
    for (int i = tid; i < HID * NCLS; i += 256) W2s[i >> 4][i & 15] = W2[i];
    __syncthreads();

    int w = tid >> 6;
    int lane = tid & 63;
    int n = blockIdx.x * 4 + w;
    int slot = lane >> 4;    // edge slot 0..3
    int p = lane & 15;       // dim-quad: dims p*4..p*4+3

    float a0 = 0.f, a1 = 0.f, a2 = 0.f, a3 = 0.f;
    float dn = 0.f;
    if (n < N) {
        dn = dis[n];
        int beg = row_ptr[n];
        int end = row_ptr[n + 1];
        int i = beg + slot;
        // 4-deep batch: all index loads issued, then all gathers -> 4x MLP
        for (; i + 12 < end; i += 16) {
            int s0 = csr_src[i];
            int s1 = csr_src[i + 4];
            int s2 = csr_src[i + 8];
            int s3 = csr_src[i + 12];
            uint2 v0 = *(const uint2*)&h1b[(size_t)s0 * HID + p * 4];
            uint2 v1 = *(const uint2*)&h1b[(size_t)s1 * HID + p * 4];
            uint2 v2 = *(const uint2*)&h1b[(size_t)s2 * HID + p * 4];
            uint2 v3 = *(const uint2*)&h1b[(size_t)s3 * HID + p * 4];
            a0 += (bflo(v0.x) + bflo(v1.x)) + (bflo(v2.x) + bflo(v3.x));
            a1 += (bfhi(v0.x) + bfhi(v1.x)) + (bfhi(v2.x) + bfhi(v3.x));
            a2 += (bflo(v0.y) + bflo(v1.y)) + (bflo(v2.y) + bflo(v3.y));
            a3 += (bfhi(v0.y) + bfhi(v1.y)) + (bfhi(v2.y) + bfhi(v3.y));
        }
        for (; i < end; i += 4) {
            int s = csr_src[i];
            uint2 v = *(const uint2*)&h1b[(size_t)s * HID + p * 4];
            a0 += bflo(v.x);
            a1 += bfhi(v.x);
            a2 += bflo(v.y);
            a3 += bfhi(v.y);
        }
    }
    // reduce across the 4 edge slots
    a0 += __shfl_xor(a0, 16, 64); a0 += __shfl_xor(a0, 32, 64);
    a1 += __shfl_xor(a1, 16, 64); a1 += __shfl_xor(a1, 32, 64);
    a2 += __shfl_xor(a2, 16, 64); a2 += __shfl_xor(a2, 32, 64);
    a3 += __shfl_xor(a3, 16, 64); a3 += __shfl_xor(a3, 32, 64);

    if (n < N && slot == 0) {
        ts[w][p * 4 + 0] = fmaxf(dn * a0 + b1[p * 4 + 0], 0.f);
        ts[w][p * 4 + 1] = fmaxf(dn * a1 + b1[p * 4 + 1], 0.f);
        ts[w][p * 4 + 2] = fmaxf(dn * a2 + b1[p * 4 + 2], 0.f);
        ts[w][p * 4 + 3] = fmaxf(dn * a3 + b1[p * 4 + 3], 0.f);
    }
    // wave-local LDS round-trip (same wave writes+reads; compiler inserts lgkmcnt)
    int q = lane >> 4;
    int c = lane & 15;
    float pacc = 0.f;
    #pragma unroll
    for (int jj = 0; jj < 16; jj++) {
        int j = q * 16 + jj;
        pacc += ts[w][j] * W2s[j][c];
    }
    pacc += __shfl_xor(pacc, 16, 64);
    pacc += __shfl_xor(pacc, 32, 64);
    if (n < N && q == 0) h2b[(size_t)n * NCLS + c] = f2bf(pacc * dn);
}

// ---------- fused layer-2 agg + epilogue ----------
// gather: 16 edge slots x 4 cls-quads, uint2 per lane -> 16 edges/instr
__global__ __launch_bounds__(256) void agg2_fused(
        const int* __restrict__ row_ptr, const int* __restrict__ csr_src,
        const unsigned short* __restrict__ h2b, const float* __restrict__ dis,
        const float* __restrict__ b2, float* __restrict__ out, int N) {
    int tid = blockIdx.x * blockDim.x + threadIdx.x;
    int n = tid >> 6;        // wave-uniform
    int lane = tid & 63;
    if (n >= N) return;      // wave-uniform exit
    int slot = lane >> 2;    // edge slot 0..15
    int p = lane & 3;        // cls-quad: classes p*4..p*4+3

    float a0 = 0.f, a1 = 0.f, a2 = 0.f, a3 = 0.f;
    int beg = row_ptr[n];
    int end = row_ptr[n + 1];
    for (int i = beg + slot; i < end; i += 16) {
        int s = csr_src[i];
        uint2 v = *(const uint2*)&h2b[(size_t)s * NCLS + p * 4];
        a0 += bflo(v.x);
        a1 += bfhi(v.x);
        a2 += bflo(v.y);
        a3 += bfhi(v.y);
    }
    #pragma unroll
    for (int m = 4; m <= 32; m <<= 1) {
        a0 += __shfl_xor(a0, m, 64);
        a1 += __shfl_xor(a1, m, 64);
        a2 += __shfl_xor(a2, m, 64);
        a3 += __shfl_xor(a3, m, 64);
    }
    if (lane < 4) {
        float dn = dis[n];
        float4 o = make_float4(dn * a0 + b2[p * 4 + 0], dn * a1 + b2[p * 4 + 1],
                               dn * a2 + b2[p * 4 + 2], dn * a3 + b2[p * 4 + 3]);
        *(float4*)&out[(size_t)n * NCLS + p * 4] = o;
    }
}

extern "C" void kernel_launch(void* const* d_in, const int* in_sizes, int n_in,
                              void* d_out, int out_size, void* d_ws, size_t ws_size,
                              hipStream_t stream) {
    const float* x   = (const float*)d_in[0];
    const int*   src = (const int*)  d_in[1];
    const int*   dst = (const int*)  d_in[2];
    const float* W1  = (const float*)d_in[3];
    const float* b1  = (const float*)d_in[4];
    const float* W2  = (const float*)d_in[5];
    const float* b2  = (const float*)d_in[6];
    float* out = (float*)d_out;
    int E = in_sizes[1];
    int N = in_sizes[0] / F_IN;
    int NB = (N + BNODES - 1) >> BSHIFT;
    int nchunks = (E + CHUNK - 1) / CHUNK;

    char* ws = (char*)d_ws;
    size_t off = 0;
    auto alloc = [&](size_t bytes) { size_t o = off; off = (off + bytes + 255) & ~(size_t)255; return (void*)(ws + o); };
    int*   bucket_count  = (int*)  alloc((size_t)NB * 4);
    int*   bucket_base   = (int*)  alloc((size_t)(NB + 1) * 4);
    int*   bucket_cursor = (int*)  alloc((size_t)NB * 4);
    int*   row_ptr       = (int*)  alloc((size_t)(N + 1) * 4);
    int*   csr_src       = (int*)  alloc((size_t)E * 4);
    float* dis           = (float*)alloc((size_t)N * 4);
    unsigned short* w1t  = (unsigned short*)alloc((size_t)F_IN * HID * 2);
    unsigned short* h1b  = (unsigned short*)alloc((size_t)N * HID * 2);
    unsigned short* h2b  = (unsigned short*)alloc((size_t)N * NCLS * 2);
    // part[] aliases h1b: dead before gemm1 writes h1b (E*4 = 6.8MB <= N*HID*2 = 12.8MB)
    unsigned int* part   = (unsigned int*)h1b;

    hipMemsetAsync(bucket_count, 0, (size_t)NB * 4, stream);

    w1t_kernel    <<<(F_IN * HID + 255) / 256, 256, 0, stream>>>(W1, w1t);
    hist_kernel   <<<nchunks, 256, 0, stream>>>(dst, bucket_count, E, NB);
    scan_buckets  <<<1, 512, 0, stream>>>(bucket_count, bucket_base, bucket_cursor, row_ptr, NB, N, E);
    scatter_kernel<<<nchunks, 256, 0, stream>>>(src, dst, bucket_cursor, part, E, NB);
    csr_build     <<<NB, 256, 0, stream>>>(part, bucket_base, csr_src, row_ptr, dis, N);
    gemm1_kernel  <<<(N + 63) / 64, 256, 0, stream>>>(x, w1t, dis, h1b, N);
    agg1_fused    <<<(N + 3) / 4, 256, 0, stream>>>(row_ptr, csr_src, h1b, dis, b1, W2, h2b, N);
    agg2_fused    <<<(N + 3) / 4, 256, 0, stream>>>(row_ptr, csr_src, h2b, dis, b2, out, N);
}